// Round 4
// baseline (7652.643 us; speedup 1.0000x reference)
//
#include <hip/hip_runtime.h>
#include <hip/hip_bf16.h>

// ---------------------------------------------------------------------------
// DispEstimator pipeline. Inputs fp32, OUTPUT fp32 (reference dtypes; the
// dataset only bf16-ROUNDS values, dtypes stay fp32). Internal activations
// stored bf16 (threshold = 2% of max|ref|), math in fp32.
// B=4, C0=64, H=W=256. Peak workspace ~160 MB (confirmed available).
// ---------------------------------------------------------------------------

typedef __hip_bfloat16 bf16;

__device__ __forceinline__ float b2f(bf16 v) { return __bfloat162float(v); }
__device__ __forceinline__ bf16  f2b(float v) { return __float2bfloat16(v); }
__device__ __forceinline__ float ldf(const float* p) { return *p; }
__device__ __forceinline__ float ldf(const bf16* p)  { return __bfloat162float(*p); }

#define WDIM 256

// gaussian kernel1d(7, sigma=1.5), normalized
__device__ __forceinline__ float gw(int j) {
    const float G[7] = {0.0366329f, 0.1112808f, 0.2167453f, 0.2706821f,
                        0.2167453f, 0.1112808f, 0.0366329f};
    return G[j];
}

// ---------------------------------------------------------------------------
// Generic 3x3 conv (zero pad = DIL), optional concat input (inA first cinA
// channels, inB the rest), optional bias. TIN in {float,bf16}; bf16 out.
// Block 256 thr. Tile 32 rows x 64 cols; each thread 8 px x 8 oc.
// Grid: (ceil(cout/8), 32, B)
// ---------------------------------------------------------------------------
template<int DIL, typename TIN>
__global__ __launch_bounds__(256) void conv3x3_k(
    const TIN* __restrict__ inA, const TIN* __restrict__ inB,
    int cinA, int cin,
    const float* __restrict__ wgt, const float* __restrict__ bias,
    bf16* __restrict__ out, int cout)
{
    constexpr int TH = 32, TW = 64;
    constexpr int PW = TW + 2 * DIL;
    constexpr int PH = TH + 2 * DIL;
    constexpr int S  = PH * PW;

    __shared__ float tile[S];
    __shared__ float wl[72];

    const int tid  = threadIdx.x;
    const int ocg  = blockIdx.x;
    const int tidx = blockIdx.y;
    const int b    = blockIdx.z;
    const int tx0  = (tidx & 3) * TW;
    const int ty0  = (tidx >> 2) * TH;

    const int py  = tid >> 3;          // 0..31
    const int px0 = (tid & 7) * 8;     // 0..56

    const int woc = tid / 9;
    const int wk  = tid - woc * 9;
    const bool wvalid = (tid < 72) && (ocg * 8 + woc < cout);

    float acc[8][8];
    #pragma unroll
    for (int a = 0; a < 8; ++a)
        #pragma unroll
        for (int p = 0; p < 8; ++p) acc[a][p] = 0.f;

    for (int ic = 0; ic < cin; ++ic) {
        const TIN* src = (ic < cinA)
            ? (inA + (((size_t)(b * cinA + ic)) << 16))
            : (inB + (((size_t)(b * (cin - cinA) + (ic - cinA))) << 16));

        for (int i = tid; i < S; i += 256) {
            int y = i / PW, x = i - y * PW;
            int gy = ty0 + y - DIL, gx = tx0 + x - DIL;
            float v = 0.f;
            if (gy >= 0 && gy < WDIM && gx >= 0 && gx < WDIM)
                v = ldf(src + (gy << 8) + gx);
            tile[i] = v;
        }
        if (tid < 72) {
            wl[tid] = wvalid
                ? wgt[((size_t)(ocg * 8 + woc) * cin + ic) * 9 + wk]
                : 0.f;
        }
        __syncthreads();

        #pragma unroll
        for (int ky = 0; ky < 3; ++ky) {
            float v[8 + 2 * DIL];
            const float* row = &tile[(py + ky * DIL) * PW + px0];
            #pragma unroll
            for (int i = 0; i < 8 + 2 * DIL; ++i) v[i] = row[i];
            #pragma unroll
            for (int oc = 0; oc < 8; ++oc) {
                const float w0 = wl[oc * 9 + ky * 3 + 0];
                const float w1 = wl[oc * 9 + ky * 3 + 1];
                const float w2 = wl[oc * 9 + ky * 3 + 2];
                #pragma unroll
                for (int px = 0; px < 8; ++px)
                    acc[oc][px] += w0 * v[px] + w1 * v[px + DIL] + w2 * v[px + 2 * DIL];
            }
        }
        __syncthreads();
    }

    #pragma unroll
    for (int oc = 0; oc < 8; ++oc) {
        int gc = ocg * 8 + oc;
        if (gc >= cout) break;
        float bv = bias ? bias[gc] : 0.f;
        size_t o = (((size_t)(b * cout + gc)) << 16) + ((ty0 + py) << 8) + tx0 + px0;
        #pragma unroll
        for (int px = 0; px < 8; ++px) out[o + px] = f2b(acc[oc][px] + bv);
    }
}

// ---------------------------------------------------------------------------
// Instance-norm stats: one block per (b,c) plane of 65536 elems.
// ---------------------------------------------------------------------------
__global__ __launch_bounds__(256) void in_stats_k(const bf16* __restrict__ x,
                                                  float* __restrict__ stats)
{
    __shared__ float rs[4], rss[4];
    const int bc = blockIdx.x;
    const bf16* p = x + (((size_t)bc) << 16);
    float s = 0.f, ss = 0.f;
    for (int i = threadIdx.x; i < 65536; i += 256) {
        float v = b2f(p[i]);
        s += v; ss += v * v;
    }
    for (int o = 32; o; o >>= 1) { s += __shfl_down(s, o); ss += __shfl_down(ss, o); }
    const int lane = threadIdx.x & 63, wid = threadIdx.x >> 6;
    if (lane == 0) { rs[wid] = s; rss[wid] = ss; }
    __syncthreads();
    if (threadIdx.x == 0) {
        s  = rs[0] + rs[1] + rs[2] + rs[3];
        ss = rss[0] + rss[1] + rss[2] + rss[3];
        float m   = s * (1.f / 65536.f);
        float var = ss * (1.f / 65536.f) - m * m;
        if (var < 0.f) var = 0.f;
        stats[2 * bc]     = m;
        stats[2 * bc + 1] = rsqrtf(var + 1e-5f);
    }
}

// normalize + affine + lrelu(0.2), in place
__global__ __launch_bounds__(256) void in_apply_k(bf16* __restrict__ x,
                                                  const float* __restrict__ stats,
                                                  const float* __restrict__ gamma,
                                                  const float* __restrict__ beta,
                                                  int C, int n)
{
    int i = blockIdx.x * 256 + threadIdx.x;
    if (i >= n) return;
    int bc = i >> 16;
    int c  = bc % C;
    float m = stats[2 * bc], r = stats[2 * bc + 1];
    float ga = gamma[c], be = beta[c];
    float t = (b2f(x[i]) - m) * r * ga + be;
    x[i] = f2b(t >= 0.f ? t : 0.2f * t);
}

// ---------------------------------------------------------------------------
// Fused blur + local correlation.
// lc[b,i*7+j,y,x] = mean_c (f2[c,y,x] - f1p[c,y+i,x+j])^2 ; f1p = zeropad3 of
// gaussian_blur(f1) (blur uses replicate edges). Blur computed in-kernel.
// Block 256 = 16x16 px tile. Grid (256 tiles, B). Also accumulates sum(lc)
// per batch into lcsum[b].
// ---------------------------------------------------------------------------
__global__ __launch_bounds__(256) void corr_k(const bf16* __restrict__ f2,
                                              const bf16* __restrict__ f1,
                                              bf16* __restrict__ lc,
                                              float* __restrict__ lcsum)
{
    __shared__ float raw[28 * 28];   // rows ty-6..ty+21, cols tx-6..tx+21
    __shared__ float hb[28 * 22];    // horiz-blurred, cols tx-3..tx+18
    __shared__ float bl[22 * 22];    // fully blurred + zero-masked
    __shared__ float red[4];

    const int tid = threadIdx.x;
    const int tx = (blockIdx.x & 15) << 4;
    const int ty = (blockIdx.x >> 4) << 4;
    const int b  = blockIdx.y;
    const int py = tid >> 4, px = tid & 15;

    float acc[49];
    #pragma unroll
    for (int k = 0; k < 49; ++k) acc[k] = 0.f;

    for (int c = 0; c < 64; ++c) {
        const size_t ch = ((size_t)(b * 64 + c)) << 16;

        for (int i = tid; i < 784; i += 256) {
            int y = i / 28, x = i - y * 28;
            int gy = ty + y - 6, gx = tx + x - 6;
            gy = gy < 0 ? 0 : (gy > 255 ? 255 : gy);
            gx = gx < 0 ? 0 : (gx > 255 ? 255 : gx);
            raw[i] = b2f(f1[ch + (gy << 8) + gx]);
        }
        __syncthreads();

        for (int i = tid; i < 616; i += 256) {   // 28 rows x 22 cols
            int r = i / 22, cc = i - r * 22;
            float s = 0.f;
            #pragma unroll
            for (int j = 0; j < 7; ++j) s += gw(j) * raw[r * 28 + cc + j];
            hb[i] = s;
        }
        __syncthreads();

        for (int i = tid; i < 484; i += 256) {   // 22 x 22
            int y = i / 22, x = i - y * 22;
            float s = 0.f;
            #pragma unroll
            for (int j = 0; j < 7; ++j) s += gw(j) * hb[(y + j) * 22 + x];
            int gy = ty + y - 3, gx = tx + x - 3;
            bl[i] = (gy >= 0 && gy < WDIM && gx >= 0 && gx < WDIM) ? s : 0.f;
        }
        __syncthreads();

        const float v2 = b2f(f2[ch + ((ty + py) << 8) + tx + px]);
        #pragma unroll
        for (int i = 0; i < 7; ++i)
            #pragma unroll
            for (int j = 0; j < 7; ++j) {
                float d = v2 - bl[(py + i) * 22 + px + j];
                acc[i * 7 + j] += d * d;
            }
        __syncthreads();
    }

    float tot = 0.f;
    #pragma unroll
    for (int k = 0; k < 49; ++k) {
        float m = acc[k] * (1.f / 64.f);
        lc[(((size_t)(b * 49 + k)) << 16) + ((ty + py) << 8) + tx + px] = f2b(m);
        tot += m;
    }
    for (int o = 32; o; o >>= 1) tot += __shfl_down(tot, o);
    if ((tid & 63) == 0) red[tid >> 6] = tot;
    __syncthreads();
    if (tid == 0) atomicAdd(lcsum + b, red[0] + red[1] + red[2] + red[3]);
}

// lc /= (mean + 1e-6), per batch, in place
__global__ __launch_bounds__(256) void lc_norm_k(bf16* __restrict__ lc,
                                                 const float* __restrict__ lcsum,
                                                 int n)
{
    int i = blockIdx.x * 256 + threadIdx.x;
    if (i >= n) return;
    int b = i / 3211264;                          // 49*65536 per batch
    float mean = lcsum[b] * (1.f / 3211264.f);
    float sc = 1.f / (mean + 1e-6f);
    lc[i] = f2b(b2f(lc[i]) * sc);
}

// ---------------------------------------------------------------------------
// Fused separable 7-tap gaussian blur (replicate edges), one (b,c) plane per
// blockIdx.y, 16x16 tile per blockIdx.x. bf16 in -> FP32 out (d_out).
// ---------------------------------------------------------------------------
__global__ __launch_bounds__(256) void blur7_k(const bf16* __restrict__ in,
                                               float* __restrict__ out)
{
    __shared__ float raw[22 * 22];   // rows ty-3..ty+18, cols tx-3..tx+18
    __shared__ float hb[22 * 16];
    const int tid = threadIdx.x;
    const int tx = (blockIdx.x & 15) << 4;
    const int ty = (blockIdx.x >> 4) << 4;
    const size_t ch = ((size_t)blockIdx.y) << 16;
    const int py = tid >> 4, px = tid & 15;

    for (int i = tid; i < 484; i += 256) {
        int y = i / 22, x = i - y * 22;
        int gy = ty + y - 3, gx = tx + x - 3;
        gy = gy < 0 ? 0 : (gy > 255 ? 255 : gy);
        gx = gx < 0 ? 0 : (gx > 255 ? 255 : gx);
        raw[i] = b2f(in[ch + (gy << 8) + gx]);
    }
    __syncthreads();
    for (int i = tid; i < 352; i += 256) {   // 22 rows x 16 cols
        int r = i >> 4, cc = i & 15;
        float s = 0.f;
        #pragma unroll
        for (int j = 0; j < 7; ++j) s += gw(j) * raw[r * 22 + cc + j];
        hb[i] = s;
    }
    __syncthreads();
    float s = 0.f;
    #pragma unroll
    for (int j = 0; j < 7; ++j) s += gw(j) * hb[(py + j) * 16 + px];
    out[ch + ((ty + py) << 8) + tx + px] = s;
}

// ---------------------------------------------------------------------------
extern "C" void kernel_launch(void* const* d_in, const int* in_sizes, int n_in,
                              void* d_out, int out_size, void* d_ws, size_t ws_size,
                              hipStream_t stream)
{
    const float* feat1  = (const float*)d_in[0];
    const float* feat2  = (const float*)d_in[1];
    const float* pre_w  = (const float*)d_in[2];
    const float* pre_b  = (const float*)d_in[3];
    const float* fc1_w  = (const float*)d_in[4];
    const float* fc1_g  = (const float*)d_in[5];
    const float* fc1_be = (const float*)d_in[6];
    const float* fc2_w  = (const float*)d_in[7];
    const float* fc2_b  = (const float*)d_in[8];
    const float* e1_w   = (const float*)d_in[9];
    const float* e1_g   = (const float*)d_in[10];
    const float* e1_be  = (const float*)d_in[11];
    const float* e2_w   = (const float*)d_in[12];
    const float* e2_g   = (const float*)d_in[13];
    const float* e2_be  = (const float*)d_in[14];
    const float* e3_w   = (const float*)d_in[15];
    const float* e3_g   = (const float*)d_in[16];
    const float* e3_be  = (const float*)d_in[17];
    const float* head_w = (const float*)d_in[18];
    const float* head_b = (const float*)d_in[19];
    float* out = (float*)d_out;

    // ---- workspace layout (bytes, bf16 activations) ----
    // A  [0,      33.5M)  pre1 out -> later fc2 out (feat)
    // B  [33.5M,  67.1M)  pre2 out -> later e1 out
    // C  [67.1M, 134.2M)  fc1 out (128ch) -> later X2/X3/HD
    // E  [134.2M,159.9M)  lc (49ch)
    const size_t NEED = 160000000;
    if (ws_size < NEED) return;

    char* ws = (char*)d_ws;
    bf16* A  = (bf16*)(ws);
    bf16* B  = (bf16*)(ws + 33554432);
    bf16* C  = (bf16*)(ws + 67108864);
    bf16* E  = (bf16*)(ws + 134217728);
    float* ST = (float*)(ws + 159907840);
    float* LS = (float*)(ws + 159911936);
    bf16* X2 = C;                                  // e2 out (32ch)
    bf16* X3 = (bf16*)(ws + 67108864 + 16777216);  // e3 out (16ch)
    bf16* HD = (bf16*)(ws + 67108864 + 25165824);  // head out (2ch)

    hipMemsetAsync(LS, 0, 4 * sizeof(float), stream);

    // 1-2. preprocessor (fp32 inputs)
    conv3x3_k<1, float><<<dim3(8, 32, 4), 256, 0, stream>>>(feat1, nullptr, 64, 64, pre_w, pre_b, A, 64);
    conv3x3_k<1, float><<<dim3(8, 32, 4), 256, 0, stream>>>(feat2, nullptr, 64, 64, pre_w, pre_b, B, 64);

    // 3. local correlation (blur fused) + normalize
    corr_k<<<dim3(256, 4), 256, 0, stream>>>(B, A, E, LS);
    lc_norm_k<<<50176, 256, 0, stream>>>(E, LS, 12845056);

    // 4. fc1: conv(cat(A,B)) -> C (128ch), IN + lrelu
    conv3x3_k<1, bf16><<<dim3(16, 32, 4), 256, 0, stream>>>(A, B, 64, 128, fc1_w, nullptr, C, 128);
    in_stats_k<<<512, 256, 0, stream>>>(C, ST);
    in_apply_k<<<131072, 256, 0, stream>>>(C, ST, fc1_g, fc1_be, 128, 33554432);

    // 5. fc2 -> feat (reuse A)
    conv3x3_k<1, bf16><<<dim3(8, 32, 4), 256, 0, stream>>>(C, nullptr, 128, 128, fc2_w, fc2_b, A, 64);

    // 6. e1: conv(cat(feat, lc)) cin=113 -> B ; IN + lrelu
    conv3x3_k<1, bf16><<<dim3(8, 32, 4), 256, 0, stream>>>(A, E, 64, 113, e1_w, nullptr, B, 64);
    in_stats_k<<<256, 256, 0, stream>>>(B, ST);
    in_apply_k<<<65536, 256, 0, stream>>>(B, ST, e1_g, e1_be, 64, 16777216);

    // 7. e2: dil=2 -> X2 (32ch) ; IN + lrelu
    conv3x3_k<2, bf16><<<dim3(4, 32, 4), 256, 0, stream>>>(B, nullptr, 64, 64, e2_w, nullptr, X2, 32);
    in_stats_k<<<128, 256, 0, stream>>>(X2, ST);
    in_apply_k<<<32768, 256, 0, stream>>>(X2, ST, e2_g, e2_be, 32, 8388608);

    // 8. e3: dil=4 -> X3 (16ch) ; IN + lrelu
    conv3x3_k<4, bf16><<<dim3(2, 32, 4), 256, 0, stream>>>(X2, nullptr, 32, 32, e3_w, nullptr, X3, 16);
    in_stats_k<<<64, 256, 0, stream>>>(X3, ST);
    in_apply_k<<<16384, 256, 0, stream>>>(X3, ST, e3_g, e3_be, 16, 4194304);

    // 9. head conv (cout=2) -> HD
    conv3x3_k<1, bf16><<<dim3(1, 32, 4), 256, 0, stream>>>(X3, nullptr, 16, 16, head_w, head_b, HD, 2);

    // 10. final gaussian blur -> out (fp32 d_out)
    blur7_k<<<dim3(256, 8), 256, 0, stream>>>(HD, out);
}

// Round 5
// 2818.392 us; speedup vs baseline: 2.7153x; 2.7153x over previous
//
#include <hip/hip_runtime.h>
#include <hip/hip_bf16.h>

// ---------------------------------------------------------------------------
// DispEstimator pipeline, MFMA bf16 implicit-GEMM version.
// Inputs fp32 NCHW, output fp32 NCHW. Internal activations NHWC bf16.
// B=4, H=W=256. Peak workspace ~152 MB (proven < available).
// ---------------------------------------------------------------------------

typedef __attribute__((ext_vector_type(8))) short short8;
typedef __attribute__((ext_vector_type(4))) float f32x4;

__device__ __forceinline__ float s2f(short s) {
    unsigned int u = ((unsigned int)(unsigned short)s) << 16;
    float f; __builtin_memcpy(&f, &u, 4); return f;
}
__device__ __forceinline__ short f2s(float f) {
    __hip_bfloat16 h = __float2bfloat16(f);
    short s; __builtin_memcpy(&s, &h, 2); return s;
}

// gaussian kernel1d(7, sigma=1.5)
__device__ __forceinline__ float gw(int j) {
    const float G[7] = {0.0366329f, 0.1112808f, 0.2167453f, 0.2706821f,
                        0.2167453f, 0.1112808f, 0.0366329f};
    return G[j];
}

// ---------------------------------------------------------------------------
// NCHW fp32 -> NHWC bf16 transpose. grid (1024, B), block 256.
// ---------------------------------------------------------------------------
__global__ __launch_bounds__(256) void transpose_k(const float* __restrict__ in,
                                                   short* __restrict__ out)
{
    __shared__ float t[64][65];
    const int b = blockIdx.y;
    const int px0 = blockIdx.x * 64;
    #pragma unroll
    for (int k = 0; k < 16; ++k) {
        int idx = threadIdx.x + k * 256;
        int c = idx >> 6, x = idx & 63;
        t[c][x] = in[(size_t)(b * 64 + c) * 65536 + px0 + x];
    }
    __syncthreads();
    #pragma unroll
    for (int k = 0; k < 16; ++k) {
        int idx = threadIdx.x + k * 256;
        int px = idx >> 6, c = idx & 63;
        out[(size_t)(b * 65536 + px0 + px) * 64 + c] = f2s(t[c][px]);
    }
}

// ---------------------------------------------------------------------------
// Weight repack: [oc][cin][3][3] fp32 -> [oc][tap][CINP] bf16, zero-padded.
// ---------------------------------------------------------------------------
__global__ __launch_bounds__(256) void repack_k(const float* __restrict__ w,
                                                short* __restrict__ o,
                                                int cout, int cin, int CINP)
{
    int idx = blockIdx.x * 256 + threadIdx.x;
    int tot = cout * 9 * CINP;
    if (idx >= tot) return;
    int ic = idx % CINP;
    int rest = idx / CINP;
    int tap = rest % 9;
    int oc = rest / 9;
    float v = (ic < cin) ? w[(size_t)(oc * cin + ic) * 9 + tap] : 0.f;
    o[idx] = f2s(v);
}

// ---------------------------------------------------------------------------
// MFMA implicit-GEMM 3x3 conv, NHWC bf16. Zero padding = DIL.
// Wave: 32 px (2 groups of 16) x 16*NOC oc. Block 4 waves (WX px x WY oc).
// K = tap*CINP + ic ; ic < splitK from srcA (stride csA) else srcB.
// grid: (XT*256, cout/(16*NOC*WY), nbatch), b = b0 + blockIdx.z.
// ---------------------------------------------------------------------------
template<int DIL, int CINP, int WY, int NOC>
__global__ __launch_bounds__(256) void convmfma_k(
    const short* __restrict__ srcA, const short* __restrict__ srcB,
    int splitK, int csA, int csB,
    const short* __restrict__ wgt, const float* __restrict__ bias,
    short* __restrict__ out, int OSTR, int OBASE, int b0)
{
    constexpr int WX = 4 / WY;
    constexpr int PXB = 32 * WX;
    constexpr int XT = 256 / PXB;
    constexpr int KTOT = 9 * CINP;

    const int lane = threadIdx.x & 63;
    const int wave = threadIdx.x >> 6;
    const int q = lane >> 4, n16 = lane & 15;
    const int wx = wave % WX, wy = wave / WX;
    const int xt = blockIdx.x % XT;
    const int y  = blockIdx.x / XT;
    const int b  = b0 + blockIdx.z;
    const int ocWaveBase = blockIdx.y * (16 * NOC * WY) + wy * (16 * NOC);
    const int x0 = xt * PXB + wx * 32;

    f32x4 acc[2][NOC];
    #pragma unroll
    for (int g = 0; g < 2; ++g)
        #pragma unroll
        for (int t = 0; t < NOC; ++t)
            acc[g][t] = {0.f, 0.f, 0.f, 0.f};

    #pragma unroll
    for (int tap = 0; tap < 9; ++tap) {
        const int dy = (tap / 3 - 1) * DIL;
        const int dx = (tap % 3 - 1) * DIL;
        const int yy = y + dy;
        const bool rowok = ((unsigned)yy < 256u);
        const int yyc = rowok ? yy : (yy < 0 ? 0 : 255);
        const int rowbase = (b * 256 + yyc) * 256;
        bool ok[2]; int xc[2];
        #pragma unroll
        for (int g = 0; g < 2; ++g) {
            int xx = x0 + g * 16 + n16 + dx;
            bool xok = ((unsigned)xx < 256u);
            ok[g] = rowok && xok;
            xc[g] = xok ? xx : (xx < 0 ? 0 : 255);
        }
        #pragma unroll
        for (int icb = 0; icb < CINP; icb += 32) {
            const int ic = icb + q * 8;
            const short* sp; int icc, cs;
            if (icb < splitK) { sp = srcA; icc = ic; cs = csA; }
            else              { sp = srcB; icc = ic - splitK; cs = csB; }
            short8 bfr[2];
            #pragma unroll
            for (int g = 0; g < 2; ++g) {
                short8 v = *reinterpret_cast<const short8*>(
                    sp + (size_t)(rowbase + xc[g]) * cs + icc);
                if (!ok[g]) v = v ^ v;   // zero fragment for padded taps
                bfr[g] = v;
            }
            #pragma unroll
            for (int t = 0; t < NOC; ++t) {
                short8 a = *reinterpret_cast<const short8*>(
                    wgt + (size_t)(ocWaveBase + t * 16 + n16) * KTOT + tap * CINP + ic);
                #pragma unroll
                for (int g = 0; g < 2; ++g)
                    acc[g][t] = __builtin_amdgcn_mfma_f32_16x16x32_bf16(
                        a, bfr[g], acc[g][t], 0, 0, 0);
            }
        }
    }

    // epilogue: lane holds, per (g,t): oc = ocWaveBase + t*16 + q*4 + r, px = x0+g*16+n16
    #pragma unroll
    for (int g = 0; g < 2; ++g) {
        const size_t px_lin = (size_t)(b * 256 + y) * 256 + x0 + g * 16 + n16;
        #pragma unroll
        for (int t = 0; t < NOC; ++t) {
            const int oc = ocWaveBase + t * 16 + q * 4;
            f32x4 v = acc[g][t];
            if (bias) {
                v.x += bias[oc];     v.y += bias[oc + 1];
                v.z += bias[oc + 2]; v.w += bias[oc + 3];
            }
            ushort4 pk;
            pk.x = (unsigned short)f2s(v.x);
            pk.y = (unsigned short)f2s(v.y);
            pk.z = (unsigned short)f2s(v.z);
            pk.w = (unsigned short)f2s(v.w);
            *reinterpret_cast<ushort4*>(out + px_lin * OSTR + OBASE + oc) = pk;
        }
    }
}

// ---------------------------------------------------------------------------
// Instance-norm partial sums, NHWC. grid (128 slices, B), block 256.
// sums[2*(b*C+c)] += sum, [..+1] += sumsq  (atomic, pre-zeroed).
// ---------------------------------------------------------------------------
__global__ __launch_bounds__(256) void in_stats_nhwc_k(const short* __restrict__ x,
                                                       float* __restrict__ sums,
                                                       int C, int lC)
{
    __shared__ float ls[256], lss[256];
    const int tid = threadIdx.x;
    const int b = blockIdx.y;
    const int c = tid & (C - 1);
    const int sub = tid >> lC;
    const int tpc = 256 >> lC;
    const int px0 = blockIdx.x * 512;
    float s = 0.f, ss = 0.f;
    for (int p = sub; p < 512; p += tpc) {
        float v = s2f(x[(size_t)(b * 65536 + px0 + p) * C + c]);
        s += v; ss += v * v;
    }
    ls[tid] = s; lss[tid] = ss;
    __syncthreads();
    if (tid < C) {
        float s0 = ls[tid], ss0 = lss[tid];
        for (int j = 1; j < tpc; ++j) { s0 += ls[tid + j * C]; ss0 += lss[tid + j * C]; }
        atomicAdd(sums + 2 * (b * C + tid), s0);
        atomicAdd(sums + 2 * (b * C + tid) + 1, ss0);
    }
}

__global__ __launch_bounds__(256) void in_finalize_k(const float* __restrict__ sums,
                                                     float* __restrict__ stats, int n)
{
    int i = blockIdx.x * 256 + threadIdx.x;
    if (i >= n) return;
    float m = sums[2 * i] * (1.f / 65536.f);
    float var = sums[2 * i + 1] * (1.f / 65536.f) - m * m;
    if (var < 0.f) var = 0.f;
    stats[2 * i] = m;
    stats[2 * i + 1] = rsqrtf(var + 1e-5f);
}

// normalize + affine + lrelu(0.2), NHWC, 4 channels/thread
__global__ __launch_bounds__(256) void in_apply_nhwc_k(short* __restrict__ x,
                                                       const float* __restrict__ stats,
                                                       const float* __restrict__ gamma,
                                                       const float* __restrict__ beta,
                                                       int C, int lC, int n4)
{
    int i = blockIdx.x * 256 + threadIdx.x;
    if (i >= n4) return;
    int e0 = i * 4;
    int c0 = e0 & (C - 1);
    int b = e0 >> (16 + lC);
    ushort4 u = reinterpret_cast<ushort4*>(x)[i];
    unsigned short vs[4] = {u.x, u.y, u.z, u.w};
    #pragma unroll
    for (int j = 0; j < 4; ++j) {
        int bc = b * C + c0 + j;
        float t = (s2f((short)vs[j]) - stats[2 * bc]) * stats[2 * bc + 1]
                  * gamma[c0 + j] + beta[c0 + j];
        vs[j] = (unsigned short)f2s(t >= 0.f ? t : 0.2f * t);
    }
    u.x = vs[0]; u.y = vs[1]; u.z = vs[2]; u.w = vs[3];
    reinterpret_cast<ushort4*>(x)[i] = u;
}

// ---------------------------------------------------------------------------
// Fused blur + local correlation, NHWC input A ([b,px,128]: f1=c0-63, f2=c64-127).
// Output lcPad [b,px,64] (49 lc + 15 zeros) + per-batch sum into lcsum.
// Block 256 = 16x16 px tile. Grid (256, B).
// ---------------------------------------------------------------------------
__global__ __launch_bounds__(256) void corr_k(const short* __restrict__ A,
                                              short* __restrict__ lcPad,
                                              float* __restrict__ lcsum)
{
    __shared__ float raw[28 * 28];
    __shared__ float hb[28 * 22];
    __shared__ float bl[22 * 22];
    __shared__ float red[4];

    const int tid = threadIdx.x;
    const int tx = (blockIdx.x & 15) << 4;
    const int ty = (blockIdx.x >> 4) << 4;
    const int b  = blockIdx.y;
    const int py = tid >> 4, px = tid & 15;

    float acc[49];
    #pragma unroll
    for (int k = 0; k < 49; ++k) acc[k] = 0.f;

    for (int c = 0; c < 64; ++c) {
        for (int i = tid; i < 784; i += 256) {
            int y = i / 28, x = i - y * 28;
            int gy = ty + y - 6, gx = tx + x - 6;
            gy = gy < 0 ? 0 : (gy > 255 ? 255 : gy);
            gx = gx < 0 ? 0 : (gx > 255 ? 255 : gx);
            raw[i] = s2f(A[(size_t)((b << 16) + (gy << 8) + gx) * 128 + c]);
        }
        __syncthreads();
        for (int i = tid; i < 616; i += 256) {
            int r = i / 22, cc = i - r * 22;
            float s = 0.f;
            #pragma unroll
            for (int j = 0; j < 7; ++j) s += gw(j) * raw[r * 28 + cc + j];
            hb[i] = s;
        }
        __syncthreads();
        for (int i = tid; i < 484; i += 256) {
            int y = i / 22, x = i - y * 22;
            float s = 0.f;
            #pragma unroll
            for (int j = 0; j < 7; ++j) s += gw(j) * hb[(y + j) * 22 + x];
            int gy = ty + y - 3, gx = tx + x - 3;
            bl[i] = (gy >= 0 && gy < 256 && gx >= 0 && gx < 256) ? s : 0.f;
        }
        __syncthreads();
        const float v2 = s2f(A[(size_t)((b << 16) + ((ty + py) << 8) + tx + px) * 128 + 64 + c]);
        #pragma unroll
        for (int i = 0; i < 7; ++i)
            #pragma unroll
            for (int j = 0; j < 7; ++j) {
                float d = v2 - bl[(py + i) * 22 + px + j];
                acc[i * 7 + j] += d * d;
            }
        __syncthreads();
    }

    const size_t base = (size_t)((b << 16) + ((ty + py) << 8) + tx + px) * 64;
    float tot = 0.f;
    #pragma unroll
    for (int k = 0; k < 49; ++k) {
        float m = acc[k] * (1.f / 64.f);
        lcPad[base + k] = f2s(m);
        tot += m;
    }
    #pragma unroll
    for (int k = 49; k < 64; ++k) lcPad[base + k] = 0;

    for (int o = 32; o; o >>= 1) tot += __shfl_down(tot, o);
    if ((tid & 63) == 0) red[tid >> 6] = tot;
    __syncthreads();
    if (tid == 0) atomicAdd(lcsum + b, red[0] + red[1] + red[2] + red[3]);
}

// lc /= (mean + 1e-6), 4 elems/thread, in place on lcPad [b,px,64]
__global__ __launch_bounds__(256) void lc_norm_k(short* __restrict__ lc,
                                                 const float* __restrict__ ls, int n4)
{
    int i = blockIdx.x * 256 + threadIdx.x;
    if (i >= n4) return;
    int b = (i * 4) >> 22;
    float sc = 1.f / (ls[b] * (1.f / 3211264.f) + 1e-6f);
    ushort4 u = reinterpret_cast<ushort4*>(lc)[i];
    u.x = (unsigned short)f2s(s2f((short)u.x) * sc);
    u.y = (unsigned short)f2s(s2f((short)u.y) * sc);
    u.z = (unsigned short)f2s(s2f((short)u.z) * sc);
    u.w = (unsigned short)f2s(s2f((short)u.w) * sc);
    reinterpret_cast<ushort4*>(lc)[i] = u;
}

// ---------------------------------------------------------------------------
// Head conv: NHWC bf16 [b,px,16] -> NCHW fp32 planes [b*2+oc][px].
// ---------------------------------------------------------------------------
__global__ __launch_bounds__(256) void head_k(const short* __restrict__ e3,
                                              const float* __restrict__ w,
                                              const float* __restrict__ bias,
                                              float* __restrict__ hd)
{
    int pix = blockIdx.x * 256 + threadIdx.x;   // 0..262143
    int b = pix >> 16, rem = pix & 65535;
    int y = rem >> 8, x = rem & 255;
    float a0 = bias[0], a1 = bias[1];
    #pragma unroll
    for (int tap = 0; tap < 9; ++tap) {
        int yy = y + tap / 3 - 1, xx = x + tap % 3 - 1;
        if ((unsigned)yy >= 256u || (unsigned)xx >= 256u) continue;
        const short* p = e3 + (size_t)((b << 16) + (yy << 8) + xx) * 16;
        #pragma unroll
        for (int ic = 0; ic < 16; ++ic) {
            float v = s2f(p[ic]);
            a0 += v * w[ic * 9 + tap];
            a1 += v * w[(16 + ic) * 9 + tap];
        }
    }
    hd[(size_t)(b * 2) * 65536 + rem]     = a0;
    hd[(size_t)(b * 2 + 1) * 65536 + rem] = a1;
}

// ---------------------------------------------------------------------------
// Final separable 7-tap gaussian blur (replicate edges), fp32 planes.
// grid (256 tiles, 8 planes).
// ---------------------------------------------------------------------------
__global__ __launch_bounds__(256) void blur7f_k(const float* __restrict__ in,
                                                float* __restrict__ out)
{
    __shared__ float raw[22 * 22];
    __shared__ float hb[22 * 16];
    const int tid = threadIdx.x;
    const int tx = (blockIdx.x & 15) << 4;
    const int ty = (blockIdx.x >> 4) << 4;
    const size_t ch = ((size_t)blockIdx.y) << 16;
    const int py = tid >> 4, px = tid & 15;

    for (int i = tid; i < 484; i += 256) {
        int y = i / 22, x = i - y * 22;
        int gy = ty + y - 3, gx = tx + x - 3;
        gy = gy < 0 ? 0 : (gy > 255 ? 255 : gy);
        gx = gx < 0 ? 0 : (gx > 255 ? 255 : gx);
        raw[i] = in[ch + (gy << 8) + gx];
    }
    __syncthreads();
    for (int i = tid; i < 352; i += 256) {
        int r = i >> 4, cc = i & 15;
        float s = 0.f;
        #pragma unroll
        for (int j = 0; j < 7; ++j) s += gw(j) * raw[r * 22 + cc + j];
        hb[i] = s;
    }
    __syncthreads();
    float s = 0.f;
    #pragma unroll
    for (int j = 0; j < 7; ++j) s += gw(j) * hb[(py + j) * 16 + px];
    out[ch + ((ty + py) << 8) + tx + px] = s;
}

// ---------------------------------------------------------------------------
extern "C" void kernel_launch(void* const* d_in, const int* in_sizes, int n_in,
                              void* d_out, int out_size, void* d_ws, size_t ws_size,
                              hipStream_t stream)
{
    const float* feat1  = (const float*)d_in[0];
    const float* feat2  = (const float*)d_in[1];
    const float* pre_w  = (const float*)d_in[2];
    const float* pre_b  = (const float*)d_in[3];
    const float* fc1_w  = (const float*)d_in[4];
    const float* fc1_g  = (const float*)d_in[5];
    const float* fc1_be = (const float*)d_in[6];
    const float* fc2_w  = (const float*)d_in[7];
    const float* fc2_b  = (const float*)d_in[8];
    const float* e1_w   = (const float*)d_in[9];
    const float* e1_g   = (const float*)d_in[10];
    const float* e1_be  = (const float*)d_in[11];
    const float* e2_w   = (const float*)d_in[12];
    const float* e2_g   = (const float*)d_in[13];
    const float* e2_be  = (const float*)d_in[14];
    const float* e3_w   = (const float*)d_in[15];
    const float* e3_g   = (const float*)d_in[16];
    const float* e3_be  = (const float*)d_in[17];
    const float* head_w = (const float*)d_in[18];
    const float* head_b = (const float*)d_in[19];
    float* out = (float*)d_out;

    // ---- workspace layout (byte offsets) ----
    // [0,33.5M)       T1  -> later lcPad
    // [33.5M,67.1M)   T2  -> later featBuf
    // [67.1M,151.0M)  A-region, 5 slots of 16,777,216 B:
    //                 A = slots 0-3; FC1o = slots 1-4 (batch-phased alias)
    //                 after fc2: E1o @67.1M, E2o @100.7M, E3o @117.4M, HD @125.8M
    // [151.0M,...)    repacked weights, IN sums/stats, lcsum
    const size_t NEED = 152000000;
    if (ws_size < NEED) return;

    char* ws = (char*)d_ws;
    short* T1      = (short*)(ws);
    short* T2      = (short*)(ws + 33554432);
    short* lcPad   = (short*)(ws);
    short* featBuf = (short*)(ws + 33554432);
    short* A       = (short*)(ws + 67108864);
    short* FC1o    = (short*)(ws + 83886080);
    short* E1o     = (short*)(ws + 67108864);
    short* E2o     = (short*)(ws + 100663296);
    short* E3o     = (short*)(ws + 117440512);
    float* HD      = (float*)(ws + 125829120);
    short* preW    = (short*)(ws + 150994944);
    short* fc1W    = (short*)(ws + 151068672);
    short* fc2W    = (short*)(ws + 151363584);
    short* e1W     = (short*)(ws + 151511040);
    short* e2W     = (short*)(ws + 151658496);
    short* e3W     = (short*)(ws + 151695360);
    float* sums0   = (float*)(ws + 151704576);
    float* sums1   = (float*)(ws + 151708672);
    float* sums2   = (float*)(ws + 151712768);
    float* sums3   = (float*)(ws + 151716864);
    float* stats0  = (float*)(ws + 151720960);
    float* stats1  = (float*)(ws + 151725056);
    float* stats2  = (float*)(ws + 151729152);
    float* stats3  = (float*)(ws + 151733248);
    float* LS      = (float*)(ws + 151737344);

    // zero the atomic-sum + lcsum area
    hipMemsetAsync(ws + 151704576, 0, 32784, stream);

    // transpose inputs to NHWC bf16
    transpose_k<<<dim3(1024, 4), 256, 0, stream>>>(feat1, T1);
    transpose_k<<<dim3(1024, 4), 256, 0, stream>>>(feat2, T2);

    // repack weights
    repack_k<<<144, 256, 0, stream>>>(pre_w, preW, 64, 64, 64);
    repack_k<<<576, 256, 0, stream>>>(fc1_w, fc1W, 128, 128, 128);
    repack_k<<<288, 256, 0, stream>>>(fc2_w, fc2W, 64, 128, 128);
    repack_k<<<288, 256, 0, stream>>>(e1_w, e1W, 64, 113, 128);
    repack_k<<<72, 256, 0, stream>>>(e2_w, e2W, 32, 64, 64);
    repack_k<<<18, 256, 0, stream>>>(e3_w, e3W, 16, 32, 32);

    // pre conv: T1 -> A channels 0-63, T2 -> A channels 64-127 (NHWC, OSTR=128)
    convmfma_k<1, 64, 2, 2><<<dim3(1024, 1, 4), 256, 0, stream>>>(
        T1, T1, 64, 64, 64, preW, pre_b, A, 128, 0, 0);
    convmfma_k<1, 64, 2, 2><<<dim3(1024, 1, 4), 256, 0, stream>>>(
        T2, T2, 64, 64, 64, preW, pre_b, A, 128, 64, 0);

    // local correlation (blur fused) -> lcPad + LS ; then normalize
    corr_k<<<dim3(256, 4), 256, 0, stream>>>(A, lcPad, LS);
    lc_norm_k<<<16384, 256, 0, stream>>>(lcPad, LS, 4194304);

    // fc1: A -> FC1o, batch-phased (b descending) so FC1o[b] aliases A[b+1]
    for (int b = 3; b >= 0; --b)
        convmfma_k<1, 128, 2, 2><<<dim3(1024, 2, 1), 256, 0, stream>>>(
            A, A, 128, 128, 128, fc1W, nullptr, FC1o, 128, 0, b);
    in_stats_nhwc_k<<<dim3(128, 4), 256, 0, stream>>>(FC1o, sums0, 128, 7);
    in_finalize_k<<<2, 256, 0, stream>>>(sums0, stats0, 512);
    in_apply_nhwc_k<<<32768, 256, 0, stream>>>(FC1o, stats0, fc1_g, fc1_be, 128, 7, 8388608);

    // fc2: FC1o -> featBuf (64ch)
    convmfma_k<1, 128, 2, 2><<<dim3(1024, 1, 4), 256, 0, stream>>>(
        FC1o, FC1o, 128, 128, 128, fc2W, fc2_b, featBuf, 64, 0, 0);

    // e1: concat(featBuf, lcPad) -> E1o (64ch)
    convmfma_k<1, 128, 2, 2><<<dim3(1024, 1, 4), 256, 0, stream>>>(
        featBuf, lcPad, 64, 64, 64, e1W, nullptr, E1o, 64, 0, 0);
    in_stats_nhwc_k<<<dim3(128, 4), 256, 0, stream>>>(E1o, sums1, 64, 6);
    in_finalize_k<<<1, 256, 0, stream>>>(sums1, stats1, 256);
    in_apply_nhwc_k<<<16384, 256, 0, stream>>>(E1o, stats1, e1_g, e1_be, 64, 6, 4194304);

    // e2: dil=2 -> E2o (32ch)
    convmfma_k<2, 64, 1, 2><<<dim3(512, 1, 4), 256, 0, stream>>>(
        E1o, E1o, 64, 64, 64, e2W, nullptr, E2o, 32, 0, 0);
    in_stats_nhwc_k<<<dim3(128, 4), 256, 0, stream>>>(E2o, sums2, 32, 5);
    in_finalize_k<<<1, 256, 0, stream>>>(sums2, stats2, 128);
    in_apply_nhwc_k<<<8192, 256, 0, stream>>>(E2o, stats2, e2_g, e2_be, 32, 5, 2097152);

    // e3: dil=4 -> E3o (16ch)
    convmfma_k<4, 32, 1, 1><<<dim3(512, 1, 4), 256, 0, stream>>>(
        E2o, E2o, 32, 32, 32, e3W, nullptr, E3o, 16, 0, 0);
    in_stats_nhwc_k<<<dim3(128, 4), 256, 0, stream>>>(E3o, sums3, 16, 4);
    in_finalize_k<<<1, 256, 0, stream>>>(sums3, stats3, 64);
    in_apply_nhwc_k<<<4096, 256, 0, stream>>>(E3o, stats3, e3_g, e3_be, 16, 4, 1048576);

    // head conv -> HD (fp32 NCHW planes), final blur -> out
    head_k<<<1024, 256, 0, stream>>>(E3o, head_w, head_b, HD);
    blur7f_k<<<dim3(256, 8), 256, 0, stream>>>(HD, out);
}

// Round 6
// 1721.161 us; speedup vs baseline: 4.4462x; 1.6375x over previous
//
#include <hip/hip_runtime.h>
#include <hip/hip_bf16.h>

// ---------------------------------------------------------------------------
// DispEstimator pipeline, MFMA bf16 implicit-GEMM version (R6).
// Inputs fp32 NCHW, output fp32 NCHW. Internal activations NHWC bf16.
// B=4, H=W=256. Peak workspace ~152 MB (proven).
// R6: corr_k rewritten with 8-channel vectorized staging (fixes 100x
// overfetch seen in R5: 3.4 GB -> ~0.15 GB); conv NOC=4 for big layers.
// ---------------------------------------------------------------------------

typedef __attribute__((ext_vector_type(8))) short short8;
typedef __attribute__((ext_vector_type(4))) float f32x4;

__device__ __forceinline__ float s2f(short s) {
    unsigned int u = ((unsigned int)(unsigned short)s) << 16;
    float f; __builtin_memcpy(&f, &u, 4); return f;
}
__device__ __forceinline__ short f2s(float f) {
    __hip_bfloat16 h = __float2bfloat16(f);
    short s; __builtin_memcpy(&s, &h, 2); return s;
}

// gaussian kernel1d(7, sigma=1.5)
__device__ __forceinline__ float gw(int j) {
    const float G[7] = {0.0366329f, 0.1112808f, 0.2167453f, 0.2706821f,
                        0.2167453f, 0.1112808f, 0.0366329f};
    return G[j];
}

// ---------------------------------------------------------------------------
// NCHW fp32 -> NHWC bf16 transpose. grid (1024, B), block 256.
// ---------------------------------------------------------------------------
__global__ __launch_bounds__(256) void transpose_k(const float* __restrict__ in,
                                                   short* __restrict__ out)
{
    __shared__ float t[64][65];
    const int b = blockIdx.y;
    const int px0 = blockIdx.x * 64;
    #pragma unroll
    for (int k = 0; k < 16; ++k) {
        int idx = threadIdx.x + k * 256;
        int c = idx >> 6, x = idx & 63;
        t[c][x] = in[(size_t)(b * 64 + c) * 65536 + px0 + x];
    }
    __syncthreads();
    #pragma unroll
    for (int k = 0; k < 16; ++k) {
        int idx = threadIdx.x + k * 256;
        int px = idx >> 6, c = idx & 63;
        out[(size_t)(b * 65536 + px0 + px) * 64 + c] = f2s(t[c][px]);
    }
}

// ---------------------------------------------------------------------------
// Weight repack: [oc][cin][3][3] fp32 -> [oc][tap][CINP] bf16, zero-padded.
// ---------------------------------------------------------------------------
__global__ __launch_bounds__(256) void repack_k(const float* __restrict__ w,
                                                short* __restrict__ o,
                                                int cout, int cin, int CINP)
{
    int idx = blockIdx.x * 256 + threadIdx.x;
    int tot = cout * 9 * CINP;
    if (idx >= tot) return;
    int ic = idx % CINP;
    int rest = idx / CINP;
    int tap = rest % 9;
    int oc = rest / 9;
    float v = (ic < cin) ? w[(size_t)(oc * cin + ic) * 9 + tap] : 0.f;
    o[idx] = f2s(v);
}

// ---------------------------------------------------------------------------
// MFMA implicit-GEMM 3x3 conv, NHWC bf16. Zero padding = DIL.
// Wave: 32 px (2 groups of 16) x 16*NOC oc. Block 4 waves (WX px x WY oc).
// K = tap*CINP + ic ; ic < splitK from srcA (stride csA) else srcB.
// grid: (XT*256, cout/(16*NOC*WY), nbatch), b = b0 + blockIdx.z.
// ---------------------------------------------------------------------------
template<int DIL, int CINP, int WY, int NOC>
__global__ __launch_bounds__(256) void convmfma_k(
    const short* __restrict__ srcA, const short* __restrict__ srcB,
    int splitK, int csA, int csB,
    const short* __restrict__ wgt, const float* __restrict__ bias,
    short* __restrict__ out, int OSTR, int OBASE, int b0)
{
    constexpr int WX = 4 / WY;
    constexpr int PXB = 32 * WX;
    constexpr int XT = 256 / PXB;
    constexpr int KTOT = 9 * CINP;

    const int lane = threadIdx.x & 63;
    const int wave = threadIdx.x >> 6;
    const int q = lane >> 4, n16 = lane & 15;
    const int wx = wave % WX, wy = wave / WX;
    const int xt = blockIdx.x % XT;
    const int y  = blockIdx.x / XT;
    const int b  = b0 + blockIdx.z;
    const int ocWaveBase = blockIdx.y * (16 * NOC * WY) + wy * (16 * NOC);
    const int x0 = xt * PXB + wx * 32;

    f32x4 acc[2][NOC];
    #pragma unroll
    for (int g = 0; g < 2; ++g)
        #pragma unroll
        for (int t = 0; t < NOC; ++t)
            acc[g][t] = {0.f, 0.f, 0.f, 0.f};

    #pragma unroll
    for (int tap = 0; tap < 9; ++tap) {
        const int dy = (tap / 3 - 1) * DIL;
        const int dx = (tap % 3 - 1) * DIL;
        const int yy = y + dy;
        const bool rowok = ((unsigned)yy < 256u);
        const int yyc = rowok ? yy : (yy < 0 ? 0 : 255);
        const int rowbase = (b * 256 + yyc) * 256;
        bool ok[2]; int xc[2];
        #pragma unroll
        for (int g = 0; g < 2; ++g) {
            int xx = x0 + g * 16 + n16 + dx;
            bool xok = ((unsigned)xx < 256u);
            ok[g] = rowok && xok;
            xc[g] = xok ? xx : (xx < 0 ? 0 : 255);
        }
        #pragma unroll
        for (int icb = 0; icb < CINP; icb += 32) {
            const int ic = icb + q * 8;
            const short* sp; int icc, cs;
            if (icb < splitK) { sp = srcA; icc = ic; cs = csA; }
            else              { sp = srcB; icc = ic - splitK; cs = csB; }
            short8 bfr[2];
            #pragma unroll
            for (int g = 0; g < 2; ++g) {
                short8 v = *reinterpret_cast<const short8*>(
                    sp + (size_t)(rowbase + xc[g]) * cs + icc);
                if (!ok[g]) v = v ^ v;   // zero fragment for padded taps
                bfr[g] = v;
            }
            #pragma unroll
            for (int t = 0; t < NOC; ++t) {
                short8 a = *reinterpret_cast<const short8*>(
                    wgt + (size_t)(ocWaveBase + t * 16 + n16) * KTOT + tap * CINP + ic);
                #pragma unroll
                for (int g = 0; g < 2; ++g)
                    acc[g][t] = __builtin_amdgcn_mfma_f32_16x16x32_bf16(
                        a, bfr[g], acc[g][t], 0, 0, 0);
            }
        }
    }

    #pragma unroll
    for (int g = 0; g < 2; ++g) {
        const size_t px_lin = (size_t)(b * 256 + y) * 256 + x0 + g * 16 + n16;
        #pragma unroll
        for (int t = 0; t < NOC; ++t) {
            const int oc = ocWaveBase + t * 16 + q * 4;
            f32x4 v = acc[g][t];
            if (bias) {
                v.x += bias[oc];     v.y += bias[oc + 1];
                v.z += bias[oc + 2]; v.w += bias[oc + 3];
            }
            ushort4 pk;
            pk.x = (unsigned short)f2s(v.x);
            pk.y = (unsigned short)f2s(v.y);
            pk.z = (unsigned short)f2s(v.z);
            pk.w = (unsigned short)f2s(v.w);
            *reinterpret_cast<ushort4*>(out + px_lin * OSTR + OBASE + oc) = pk;
        }
    }
}

// ---------------------------------------------------------------------------
// Instance-norm partial sums, NHWC. grid (128 slices, B), block 256.
// ---------------------------------------------------------------------------
__global__ __launch_bounds__(256) void in_stats_nhwc_k(const short* __restrict__ x,
                                                       float* __restrict__ sums,
                                                       int C, int lC)
{
    __shared__ float ls[256], lss[256];
    const int tid = threadIdx.x;
    const int b = blockIdx.y;
    const int c = tid & (C - 1);
    const int sub = tid >> lC;
    const int tpc = 256 >> lC;
    const int px0 = blockIdx.x * 512;
    float s = 0.f, ss = 0.f;
    for (int p = sub; p < 512; p += tpc) {
        float v = s2f(x[(size_t)(b * 65536 + px0 + p) * C + c]);
        s += v; ss += v * v;
    }
    ls[tid] = s; lss[tid] = ss;
    __syncthreads();
    if (tid < C) {
        float s0 = ls[tid], ss0 = lss[tid];
        for (int j = 1; j < tpc; ++j) { s0 += ls[tid + j * C]; ss0 += lss[tid + j * C]; }
        atomicAdd(sums + 2 * (b * C + tid), s0);
        atomicAdd(sums + 2 * (b * C + tid) + 1, ss0);
    }
}

__global__ __launch_bounds__(256) void in_finalize_k(const float* __restrict__ sums,
                                                     float* __restrict__ stats, int n)
{
    int i = blockIdx.x * 256 + threadIdx.x;
    if (i >= n) return;
    float m = sums[2 * i] * (1.f / 65536.f);
    float var = sums[2 * i + 1] * (1.f / 65536.f) - m * m;
    if (var < 0.f) var = 0.f;
    stats[2 * i] = m;
    stats[2 * i + 1] = rsqrtf(var + 1e-5f);
}

// normalize + affine + lrelu(0.2), NHWC, 4 channels/thread
__global__ __launch_bounds__(256) void in_apply_nhwc_k(short* __restrict__ x,
                                                       const float* __restrict__ stats,
                                                       const float* __restrict__ gamma,
                                                       const float* __restrict__ beta,
                                                       int C, int lC, int n4)
{
    int i = blockIdx.x * 256 + threadIdx.x;
    if (i >= n4) return;
    int e0 = i * 4;
    int c0 = e0 & (C - 1);
    int b = e0 >> (16 + lC);
    ushort4 u = reinterpret_cast<ushort4*>(x)[i];
    unsigned short vs[4] = {u.x, u.y, u.z, u.w};
    #pragma unroll
    for (int j = 0; j < 4; ++j) {
        int bc = b * C + c0 + j;
        float t = (s2f((short)vs[j]) - stats[2 * bc]) * stats[2 * bc + 1]
                  * gamma[c0 + j] + beta[c0 + j];
        vs[j] = (unsigned short)f2s(t >= 0.f ? t : 0.2f * t);
    }
    u.x = vs[0]; u.y = vs[1]; u.z = vs[2]; u.w = vs[3];
    reinterpret_cast<ushort4*>(x)[i] = u;
}

// ---------------------------------------------------------------------------
// Fused blur + local correlation v2: 8-channel vectorized staging.
// A NHWC [b,px,128]: f1 = ch 0-63, f2 = ch 64-127.
// Per channel-group g (8 ch): stage 28x28x8 halo (short8 loads), h-blur ->
// 28x22x8 fp32, v-blur+zeromask -> 22x22x8 fp32, accumulate 49 offsets.
// Output lcPad [b,px,64] (49 lc + 15 zeros) + per-batch sum into lcsum.
// Block 256 = 16x16 px tile. Grid (256, B).
// ---------------------------------------------------------------------------
__global__ __launch_bounds__(256) void corr_k(const short* __restrict__ A,
                                              short* __restrict__ lcPad,
                                              float* __restrict__ lcsum)
{
    __shared__ __align__(16) short raw[28 * 28 * 8];   // 12.5 KB
    __shared__ __align__(16) float hb[28 * 22 * 8];    // 19.7 KB
    __shared__ __align__(16) float bl[22 * 22 * 8];    // 15.5 KB
    __shared__ float red[4];

    const int tid = threadIdx.x;
    const int tx = (blockIdx.x & 15) << 4;
    const int ty = (blockIdx.x >> 4) << 4;
    const int b  = blockIdx.y;
    const int py = tid >> 4, px = tid & 15;

    float acc[49];
    #pragma unroll
    for (int k = 0; k < 49; ++k) acc[k] = 0.f;

    for (int g = 0; g < 8; ++g) {
        const int c0 = g * 8;

        // stage raw halo tile (replicate-clamp coords for blur)
        for (int i = tid; i < 784; i += 256) {
            int y = i / 28, x = i - y * 28;
            int gy = ty + y - 6, gx = tx + x - 6;
            gy = gy < 0 ? 0 : (gy > 255 ? 255 : gy);
            gx = gx < 0 ? 0 : (gx > 255 ? 255 : gx);
            *reinterpret_cast<short8*>(&raw[i * 8]) =
                *reinterpret_cast<const short8*>(
                    &A[(size_t)((b << 16) + (gy << 8) + gx) * 128 + c0]);
        }
        __syncthreads();

        // horizontal blur: 28 rows x 22 cols x 8 ch
        for (int i = tid; i < 616; i += 256) {
            int r = i / 22, cc = i - r * 22;
            float s[8];
            #pragma unroll
            for (int c = 0; c < 8; ++c) s[c] = 0.f;
            #pragma unroll
            for (int j = 0; j < 7; ++j) {
                short8 v = *reinterpret_cast<const short8*>(&raw[(r * 28 + cc + j) * 8]);
                float w = gw(j);
                #pragma unroll
                for (int c = 0; c < 8; ++c) s[c] += w * s2f(v[c]);
            }
            #pragma unroll
            for (int c = 0; c < 8; ++c) hb[i * 8 + c] = s[c];
        }
        __syncthreads();

        // vertical blur + zero-mask (lc uses zero-pad of blurred f1)
        for (int i = tid; i < 484; i += 256) {
            int y = i / 22, x = i - y * 22;
            float s[8];
            #pragma unroll
            for (int c = 0; c < 8; ++c) s[c] = 0.f;
            #pragma unroll
            for (int j = 0; j < 7; ++j) {
                const float* hp = &hb[((y + j) * 22 + x) * 8];
                float w = gw(j);
                #pragma unroll
                for (int c = 0; c < 8; ++c) s[c] += w * hp[c];
            }
            int gy = ty + y - 3, gx = tx + x - 3;
            bool okp = (gy >= 0 && gy < 256 && gx >= 0 && gx < 256);
            #pragma unroll
            for (int c = 0; c < 8; ++c) bl[i * 8 + c] = okp ? s[c] : 0.f;
        }
        __syncthreads();

        // f2 channels for this pixel/group
        short8 f2v = *reinterpret_cast<const short8*>(
            &A[(size_t)((b << 16) + ((ty + py) << 8) + tx + px) * 128 + 64 + c0]);
        float f2f[8];
        #pragma unroll
        for (int c = 0; c < 8; ++c) f2f[c] = s2f(f2v[c]);

        const float* blp = &bl[(py * 22 + px) * 8];
        #pragma unroll
        for (int i = 0; i < 7; ++i)
            #pragma unroll
            for (int j = 0; j < 7; ++j) {
                const f32x4* q = reinterpret_cast<const f32x4*>(blp + (i * 22 + j) * 8);
                f32x4 lo = q[0], hi = q[1];
                float a = acc[i * 7 + j];
                float d;
                d = f2f[0] - lo.x; a += d * d;
                d = f2f[1] - lo.y; a += d * d;
                d = f2f[2] - lo.z; a += d * d;
                d = f2f[3] - lo.w; a += d * d;
                d = f2f[4] - hi.x; a += d * d;
                d = f2f[5] - hi.y; a += d * d;
                d = f2f[6] - hi.z; a += d * d;
                d = f2f[7] - hi.w; a += d * d;
                acc[i * 7 + j] = a;
            }
        __syncthreads();
    }

    const size_t base = (size_t)((b << 16) + ((ty + py) << 8) + tx + px) * 64;
    float tot = 0.f;
    #pragma unroll
    for (int k = 0; k < 49; ++k) {
        float m = acc[k] * (1.f / 64.f);
        lcPad[base + k] = f2s(m);
        tot += m;
    }
    #pragma unroll
    for (int k = 49; k < 64; ++k) lcPad[base + k] = 0;

    for (int o = 32; o; o >>= 1) tot += __shfl_down(tot, o);
    if ((tid & 63) == 0) red[tid >> 6] = tot;
    __syncthreads();
    if (tid == 0) atomicAdd(lcsum + b, red[0] + red[1] + red[2] + red[3]);
}

// lc /= (mean + 1e-6), 4 elems/thread, in place on lcPad [b,px,64]
__global__ __launch_bounds__(256) void lc_norm_k(short* __restrict__ lc,
                                                 const float* __restrict__ ls, int n4)
{
    int i = blockIdx.x * 256 + threadIdx.x;
    if (i >= n4) return;
    int b = (i * 4) >> 22;
    float sc = 1.f / (ls[b] * (1.f / 3211264.f) + 1e-6f);
    ushort4 u = reinterpret_cast<ushort4*>(lc)[i];
    u.x = (unsigned short)f2s(s2f((short)u.x) * sc);
    u.y = (unsigned short)f2s(s2f((short)u.y) * sc);
    u.z = (unsigned short)f2s(s2f((short)u.z) * sc);
    u.w = (unsigned short)f2s(s2f((short)u.w) * sc);
    reinterpret_cast<ushort4*>(lc)[i] = u;
}

// ---------------------------------------------------------------------------
// Head conv: NHWC bf16 [b,px,16] -> NCHW fp32 planes [b*2+oc][px].
// ---------------------------------------------------------------------------
__global__ __launch_bounds__(256) void head_k(const short* __restrict__ e3,
                                              const float* __restrict__ w,
                                              const float* __restrict__ bias,
                                              float* __restrict__ hd)
{
    int pix = blockIdx.x * 256 + threadIdx.x;
    int b = pix >> 16, rem = pix & 65535;
    int y = rem >> 8, x = rem & 255;
    float a0 = bias[0], a1 = bias[1];
    #pragma unroll
    for (int tap = 0; tap < 9; ++tap) {
        int yy = y + tap / 3 - 1, xx = x + tap % 3 - 1;
        if ((unsigned)yy >= 256u || (unsigned)xx >= 256u) continue;
        const short* p = e3 + (size_t)((b << 16) + (yy << 8) + xx) * 16;
        #pragma unroll
        for (int ic = 0; ic < 16; ++ic) {
            float v = s2f(p[ic]);
            a0 += v * w[ic * 9 + tap];
            a1 += v * w[(16 + ic) * 9 + tap];
        }
    }
    hd[(size_t)(b * 2) * 65536 + rem]     = a0;
    hd[(size_t)(b * 2 + 1) * 65536 + rem] = a1;
}

// ---------------------------------------------------------------------------
// Final separable 7-tap gaussian blur (replicate edges), fp32 planes.
// ---------------------------------------------------------------------------
__global__ __launch_bounds__(256) void blur7f_k(const float* __restrict__ in,
                                                float* __restrict__ out)
{
    __shared__ float raw[22 * 22];
    __shared__ float hb[22 * 16];
    const int tid = threadIdx.x;
    const int tx = (blockIdx.x & 15) << 4;
    const int ty = (blockIdx.x >> 4) << 4;
    const size_t ch = ((size_t)blockIdx.y) << 16;
    const int py = tid >> 4, px = tid & 15;

    for (int i = tid; i < 484; i += 256) {
        int y = i / 22, x = i - y * 22;
        int gy = ty + y - 3, gx = tx + x - 3;
        gy = gy < 0 ? 0 : (gy > 255 ? 255 : gy);
        gx = gx < 0 ? 0 : (gx > 255 ? 255 : gx);
        raw[i] = in[ch + (gy << 8) + gx];
    }
    __syncthreads();
    for (int i = tid; i < 352; i += 256) {
        int r = i >> 4, cc = i & 15;
        float s = 0.f;
        #pragma unroll
        for (int j = 0; j < 7; ++j) s += gw(j) * raw[r * 22 + cc + j];
        hb[i] = s;
    }
    __syncthreads();
    float s = 0.f;
    #pragma unroll
    for (int j = 0; j < 7; ++j) s += gw(j) * hb[(py + j) * 16 + px];
    out[ch + ((ty + py) << 8) + tx + px] = s;
}

// ---------------------------------------------------------------------------
extern "C" void kernel_launch(void* const* d_in, const int* in_sizes, int n_in,
                              void* d_out, int out_size, void* d_ws, size_t ws_size,
                              hipStream_t stream)
{
    const float* feat1  = (const float*)d_in[0];
    const float* feat2  = (const float*)d_in[1];
    const float* pre_w  = (const float*)d_in[2];
    const float* pre_b  = (const float*)d_in[3];
    const float* fc1_w  = (const float*)d_in[4];
    const float* fc1_g  = (const float*)d_in[5];
    const float* fc1_be = (const float*)d_in[6];
    const float* fc2_w  = (const float*)d_in[7];
    const float* fc2_b  = (const float*)d_in[8];
    const float* e1_w   = (const float*)d_in[9];
    const float* e1_g   = (const float*)d_in[10];
    const float* e1_be  = (const float*)d_in[11];
    const float* e2_w   = (const float*)d_in[12];
    const float* e2_g   = (const float*)d_in[13];
    const float* e2_be  = (const float*)d_in[14];
    const float* e3_w   = (const float*)d_in[15];
    const float* e3_g   = (const float*)d_in[16];
    const float* e3_be  = (const float*)d_in[17];
    const float* head_w = (const float*)d_in[18];
    const float* head_b = (const float*)d_in[19];
    float* out = (float*)d_out;

    const size_t NEED = 152000000;
    if (ws_size < NEED) return;

    char* ws = (char*)d_ws;
    short* T1      = (short*)(ws);
    short* T2      = (short*)(ws + 33554432);
    short* lcPad   = (short*)(ws);
    short* featBuf = (short*)(ws + 33554432);
    short* A       = (short*)(ws + 67108864);
    short* FC1o    = (short*)(ws + 83886080);
    short* E1o     = (short*)(ws + 67108864);
    short* E2o     = (short*)(ws + 100663296);
    short* E3o     = (short*)(ws + 117440512);
    float* HD      = (float*)(ws + 125829120);
    short* preW    = (short*)(ws + 150994944);
    short* fc1W    = (short*)(ws + 151068672);
    short* fc2W    = (short*)(ws + 151363584);
    short* e1W     = (short*)(ws + 151511040);
    short* e2W     = (short*)(ws + 151658496);
    short* e3W     = (short*)(ws + 151695360);
    float* sums0   = (float*)(ws + 151704576);
    float* sums1   = (float*)(ws + 151708672);
    float* sums2   = (float*)(ws + 151712768);
    float* sums3   = (float*)(ws + 151716864);
    float* stats0  = (float*)(ws + 151720960);
    float* stats1  = (float*)(ws + 151725056);
    float* stats2  = (float*)(ws + 151729152);
    float* stats3  = (float*)(ws + 151733248);
    float* LS      = (float*)(ws + 151737344);

    hipMemsetAsync(ws + 151704576, 0, 32784, stream);

    transpose_k<<<dim3(1024, 4), 256, 0, stream>>>(feat1, T1);
    transpose_k<<<dim3(1024, 4), 256, 0, stream>>>(feat2, T2);

    repack_k<<<144, 256, 0, stream>>>(pre_w, preW, 64, 64, 64);
    repack_k<<<576, 256, 0, stream>>>(fc1_w, fc1W, 128, 128, 128);
    repack_k<<<288, 256, 0, stream>>>(fc2_w, fc2W, 64, 128, 128);
    repack_k<<<288, 256, 0, stream>>>(e1_w, e1W, 64, 113, 128);
    repack_k<<<72, 256, 0, stream>>>(e2_w, e2W, 32, 64, 64);
    repack_k<<<18, 256, 0, stream>>>(e3_w, e3W, 16, 32, 32);

    // pre conv (cout=64): NOC=4, WY=1 -> block 128px x 64oc
    convmfma_k<1, 64, 1, 4><<<dim3(512, 1, 4), 256, 0, stream>>>(
        T1, T1, 64, 64, 64, preW, pre_b, A, 128, 0, 0);
    convmfma_k<1, 64, 1, 4><<<dim3(512, 1, 4), 256, 0, stream>>>(
        T2, T2, 64, 64, 64, preW, pre_b, A, 128, 64, 0);

    // local correlation (vectorized, blur fused) + normalize
    corr_k<<<dim3(256, 4), 256, 0, stream>>>(A, lcPad, LS);
    lc_norm_k<<<16384, 256, 0, stream>>>(lcPad, LS, 4194304);

    // fc1 (cout=128): NOC=4, WY=2 -> block 64px x 128oc; batch-phased alias
    for (int b = 3; b >= 0; --b)
        convmfma_k<1, 128, 2, 4><<<dim3(1024, 1, 1), 256, 0, stream>>>(
            A, A, 128, 128, 128, fc1W, nullptr, FC1o, 128, 0, b);
    in_stats_nhwc_k<<<dim3(128, 4), 256, 0, stream>>>(FC1o, sums0, 128, 7);
    in_finalize_k<<<2, 256, 0, stream>>>(sums0, stats0, 512);
    in_apply_nhwc_k<<<32768, 256, 0, stream>>>(FC1o, stats0, fc1_g, fc1_be, 128, 7, 8388608);

    // fc2 (cout=64): NOC=4, WY=1
    convmfma_k<1, 128, 1, 4><<<dim3(512, 1, 4), 256, 0, stream>>>(
        FC1o, FC1o, 128, 128, 128, fc2W, fc2_b, featBuf, 64, 0, 0);

    // e1 (cout=64): NOC=4, WY=1 ; concat(featBuf, lcPad)
    convmfma_k<1, 128, 1, 4><<<dim3(512, 1, 4), 256, 0, stream>>>(
        featBuf, lcPad, 64, 64, 64, e1W, nullptr, E1o, 64, 0, 0);
    in_stats_nhwc_k<<<dim3(128, 4), 256, 0, stream>>>(E1o, sums1, 64, 6);
    in_finalize_k<<<1, 256, 0, stream>>>(sums1, stats1, 256);
    in_apply_nhwc_k<<<16384, 256, 0, stream>>>(E1o, stats1, e1_g, e1_be, 64, 6, 4194304);

    // e2 (cout=32): dil=2, NOC=2, WY=1
    convmfma_k<2, 64, 1, 2><<<dim3(512, 1, 4), 256, 0, stream>>>(
        E1o, E1o, 64, 64, 64, e2W, nullptr, E2o, 32, 0, 0);
    in_stats_nhwc_k<<<dim3(128, 4), 256, 0, stream>>>(E2o, sums2, 32, 5);
    in_finalize_k<<<1, 256, 0, stream>>>(sums2, stats2, 128);
    in_apply_nhwc_k<<<8192, 256, 0, stream>>>(E2o, stats2, e2_g, e2_be, 32, 5, 2097152);

    // e3 (cout=16): dil=4, NOC=1, WY=1
    convmfma_k<4, 32, 1, 1><<<dim3(512, 1, 4), 256, 0, stream>>>(
        E2o, E2o, 32, 32, 32, e3W, nullptr, E3o, 16, 0, 0);
    in_stats_nhwc_k<<<dim3(128, 4), 256, 0, stream>>>(E3o, sums3, 16, 4);
    in_finalize_k<<<1, 256, 0, stream>>>(sums3, stats3, 64);
    in_apply_nhwc_k<<<4096, 256, 0, stream>>>(E3o, stats3, e3_g, e3_be, 16, 4, 1048576);

    head_k<<<1024, 256, 0, stream>>>(E3o, head_w, head_b, HD);
    blur7f_k<<<dim3(256, 8), 256, 0, stream>>>(HD, out);
}

// Round 7
// 1285.203 us; speedup vs baseline: 5.9544x; 1.3392x over previous
//
#include <hip/hip_runtime.h>
#include <hip/hip_bf16.h>

// ---------------------------------------------------------------------------
// DispEstimator pipeline, MFMA bf16 implicit-GEMM (R7).
// R7: weights repacked to MFMA-native [oc16][tap][kblk][lane][8] so A-frag
// loads are 1KB coalesced; wave px-tile G=4 (16 MFMA / 8 loads); corr LDS
// padded (stride 12 floats) to kill 4/8-way bank conflicts.
// ---------------------------------------------------------------------------

typedef __attribute__((ext_vector_type(8))) short short8;
typedef __attribute__((ext_vector_type(4))) float f32x4;

__device__ __forceinline__ float s2f(short s) {
    unsigned int u = ((unsigned int)(unsigned short)s) << 16;
    float f; __builtin_memcpy(&f, &u, 4); return f;
}
__device__ __forceinline__ short f2s(float f) {
    __hip_bfloat16 h = __float2bfloat16(f);
    short s; __builtin_memcpy(&s, &h, 2); return s;
}

__device__ __forceinline__ float gw(int j) {
    const float G[7] = {0.0366329f, 0.1112808f, 0.2167453f, 0.2706821f,
                        0.2167453f, 0.1112808f, 0.0366329f};
    return G[j];
}

// ---------------------------------------------------------------------------
// NCHW fp32 -> NHWC bf16 transpose. grid (1024, B), block 256.
// ---------------------------------------------------------------------------
__global__ __launch_bounds__(256) void transpose_k(const float* __restrict__ in,
                                                   short* __restrict__ out)
{
    __shared__ float t[64][65];
    const int b = blockIdx.y;
    const int px0 = blockIdx.x * 64;
    #pragma unroll
    for (int k = 0; k < 16; ++k) {
        int idx = threadIdx.x + k * 256;
        int c = idx >> 6, x = idx & 63;
        t[c][x] = in[(size_t)(b * 64 + c) * 65536 + px0 + x];
    }
    __syncthreads();
    #pragma unroll
    for (int k = 0; k < 16; ++k) {
        int idx = threadIdx.x + k * 256;
        int px = idx >> 6, c = idx & 63;
        out[(size_t)(b * 65536 + px0 + px) * 64 + c] = f2s(t[c][px]);
    }
}

// ---------------------------------------------------------------------------
// Weight repack v2: [oc][cin][3][3] fp32 -> MFMA-native
// [o16][tap][cb][lane][8] bf16 (o16 = oc/16, cb = k-block of 32, lane=q*16+n16;
// element (lane,c8) <-> oc = o16*16+n16, ic = cb*32+q*8+c8). Zero-padded.
// ---------------------------------------------------------------------------
__global__ __launch_bounds__(256) void repack2_k(const float* __restrict__ w,
                                                 short* __restrict__ o,
                                                 int cout, int cin, int CINP)
{
    int idx = blockIdx.x * 256 + threadIdx.x;
    int CB = CINP >> 5;
    int tot = cout * 9 * CINP;
    if (idx >= tot) return;
    int c8   = idx & 7;
    int lane = (idx >> 3) & 63;
    int rest = idx >> 9;          // ((o16*9+tap)*CB + cb)
    int cb   = rest % CB;
    int rest2 = rest / CB;
    int tap  = rest2 % 9;
    int o16  = rest2 / 9;
    int n16 = lane & 15, q = lane >> 4;
    int oc = o16 * 16 + n16;
    int ic = cb * 32 + q * 8 + c8;
    float v = (ic < cin) ? w[(size_t)(oc * cin + ic) * 9 + tap] : 0.f;
    o[idx] = f2s(v);
}

// ---------------------------------------------------------------------------
// MFMA implicit-GEMM 3x3 conv, NHWC bf16, zero pad = DIL.
// Wave: G*16 px x 16*NOC oc. Block 4 waves (WX px-groups x WY oc-groups).
// Weights in MFMA-native layout (repack2_k). grid:(XT*256, cout/(16*NOC*WY), nb)
// ---------------------------------------------------------------------------
template<int DIL, int CINP, int WY, int NOC, int G>
__global__ __launch_bounds__(256) void convmfma_k(
    const short* __restrict__ srcA, const short* __restrict__ srcB,
    int splitK, int csA, int csB,
    const short* __restrict__ wgt, const float* __restrict__ bias,
    short* __restrict__ out, int OSTR, int OBASE, int b0)
{
    constexpr int WX  = 4 / WY;
    constexpr int PXW = G * 16;
    constexpr int PXB = PXW * WX;
    constexpr int XT  = 256 / PXB;
    constexpr int CB  = CINP / 32;

    const int lane = threadIdx.x & 63;
    const int wave = threadIdx.x >> 6;
    const int q = lane >> 4, n16 = lane & 15;
    const int wx = wave % WX, wy = wave / WX;
    const int xt = blockIdx.x % XT;
    const int y  = blockIdx.x / XT;
    const int b  = b0 + blockIdx.z;
    const int ocWaveBase = blockIdx.y * (16 * NOC * WY) + wy * (16 * NOC);
    const int o16base = ocWaveBase >> 4;
    const int x0 = xt * PXB + wx * PXW;

    f32x4 acc[G][NOC];
    #pragma unroll
    for (int g = 0; g < G; ++g)
        #pragma unroll
        for (int t = 0; t < NOC; ++t)
            acc[g][t] = {0.f, 0.f, 0.f, 0.f};

    #pragma unroll
    for (int tap = 0; tap < 9; ++tap) {
        const int dy = (tap / 3 - 1) * DIL;
        const int dx = (tap % 3 - 1) * DIL;
        const int yy = y + dy;
        const bool rowok = ((unsigned)yy < 256u);
        const int yyc = rowok ? yy : (yy < 0 ? 0 : 255);
        const int rowbase = (b * 256 + yyc) * 256;
        bool ok[G]; int xc[G];
        #pragma unroll
        for (int g = 0; g < G; ++g) {
            int xx = x0 + g * 16 + n16 + dx;
            bool xok = ((unsigned)xx < 256u);
            ok[g] = rowok && xok;
            xc[g] = xok ? xx : (xx < 0 ? 0 : 255);
        }
        #pragma unroll
        for (int cb = 0; cb < CB; ++cb) {
            const int icb = cb * 32;
            const int ic = icb + q * 8;
            const short* sp; int icc, cs;
            if (icb < splitK) { sp = srcA; icc = ic; cs = csA; }
            else              { sp = srcB; icc = ic - splitK; cs = csB; }
            short8 bfr[G];
            #pragma unroll
            for (int g = 0; g < G; ++g) {
                short8 v = *reinterpret_cast<const short8*>(
                    sp + (size_t)(rowbase + xc[g]) * cs + icc);
                if (!ok[g]) v = v ^ v;
                bfr[g] = v;
            }
            #pragma unroll
            for (int t = 0; t < NOC; ++t) {
                short8 a = *reinterpret_cast<const short8*>(
                    wgt + ((((size_t)(o16base + t) * 9 + tap) * CB + cb) * 64 + lane) * 8);
                #pragma unroll
                for (int g = 0; g < G; ++g)
                    acc[g][t] = __builtin_amdgcn_mfma_f32_16x16x32_bf16(
                        a, bfr[g], acc[g][t], 0, 0, 0);
            }
        }
    }

    #pragma unroll
    for (int g = 0; g < G; ++g) {
        const size_t px_lin = (size_t)(b * 256 + y) * 256 + x0 + g * 16 + n16;
        #pragma unroll
        for (int t = 0; t < NOC; ++t) {
            const int oc = ocWaveBase + t * 16 + q * 4;
            f32x4 v = acc[g][t];
            if (bias) {
                v.x += bias[oc];     v.y += bias[oc + 1];
                v.z += bias[oc + 2]; v.w += bias[oc + 3];
            }
            ushort4 pk;
            pk.x = (unsigned short)f2s(v.x);
            pk.y = (unsigned short)f2s(v.y);
            pk.z = (unsigned short)f2s(v.z);
            pk.w = (unsigned short)f2s(v.w);
            *reinterpret_cast<ushort4*>(out + px_lin * OSTR + OBASE + oc) = pk;
        }
    }
}

// ---------------------------------------------------------------------------
// Instance-norm partial sums, NHWC. grid (128 slices, B), block 256.
// ---------------------------------------------------------------------------
__global__ __launch_bounds__(256) void in_stats_nhwc_k(const short* __restrict__ x,
                                                       float* __restrict__ sums,
                                                       int C, int lC)
{
    __shared__ float ls[256], lss[256];
    const int tid = threadIdx.x;
    const int b = blockIdx.y;
    const int c = tid & (C - 1);
    const int sub = tid >> lC;
    const int tpc = 256 >> lC;
    const int px0 = blockIdx.x * 512;
    float s = 0.f, ss = 0.f;
    for (int p = sub; p < 512; p += tpc) {
        float v = s2f(x[(size_t)(b * 65536 + px0 + p) * C + c]);
        s += v; ss += v * v;
    }
    ls[tid] = s; lss[tid] = ss;
    __syncthreads();
    if (tid < C) {
        float s0 = ls[tid], ss0 = lss[tid];
        for (int j = 1; j < tpc; ++j) { s0 += ls[tid + j * C]; ss0 += lss[tid + j * C]; }
        atomicAdd(sums + 2 * (b * C + tid), s0);
        atomicAdd(sums + 2 * (b * C + tid) + 1, ss0);
    }
}

__global__ __launch_bounds__(256) void in_finalize_k(const float* __restrict__ sums,
                                                     float* __restrict__ stats, int n)
{
    int i = blockIdx.x * 256 + threadIdx.x;
    if (i >= n) return;
    float m = sums[2 * i] * (1.f / 65536.f);
    float var = sums[2 * i + 1] * (1.f / 65536.f) - m * m;
    if (var < 0.f) var = 0.f;
    stats[2 * i] = m;
    stats[2 * i + 1] = rsqrtf(var + 1e-5f);
}

__global__ __launch_bounds__(256) void in_apply_nhwc_k(short* __restrict__ x,
                                                       const float* __restrict__ stats,
                                                       const float* __restrict__ gamma,
                                                       const float* __restrict__ beta,
                                                       int C, int lC, int n4)
{
    int i = blockIdx.x * 256 + threadIdx.x;
    if (i >= n4) return;
    int e0 = i * 4;
    int c0 = e0 & (C - 1);
    int b = e0 >> (16 + lC);
    ushort4 u = reinterpret_cast<ushort4*>(x)[i];
    unsigned short vs[4] = {u.x, u.y, u.z, u.w};
    #pragma unroll
    for (int j = 0; j < 4; ++j) {
        int bc = b * C + c0 + j;
        float t = (s2f((short)vs[j]) - stats[2 * bc]) * stats[2 * bc + 1]
                  * gamma[c0 + j] + beta[c0 + j];
        vs[j] = (unsigned short)f2s(t >= 0.f ? t : 0.2f * t);
    }
    u.x = vs[0]; u.y = vs[1]; u.z = vs[2]; u.w = vs[3];
    reinterpret_cast<ushort4*>(x)[i] = u;
}

// ---------------------------------------------------------------------------
// Fused blur + local correlation (8-ch groups, padded LDS: stride 12 floats
// per cell -> 2-way max bank aliasing). A NHWC [b,px,128]: f1 ch0-63, f2 ch64+.
// Block 256 = 16x16 px. Grid (256, B).
// ---------------------------------------------------------------------------
__global__ __launch_bounds__(256) void corr_k(const short* __restrict__ A,
                                              short* __restrict__ lcPad,
                                              float* __restrict__ lcsum)
{
    __shared__ __align__(16) short raw[28 * 28 * 8];    // 12.5 KB
    __shared__ __align__(16) float hb[28 * 22 * 12];    // 29.6 KB (pad 8->12)
    __shared__ __align__(16) float bl[22 * 22 * 12];    // 23.2 KB (pad 8->12)
    __shared__ float red[4];

    const int tid = threadIdx.x;
    const int tx = (blockIdx.x & 15) << 4;
    const int ty = (blockIdx.x >> 4) << 4;
    const int b  = blockIdx.y;
    const int py = tid >> 4, px = tid & 15;

    float acc[49];
    #pragma unroll
    for (int k = 0; k < 49; ++k) acc[k] = 0.f;

    for (int g = 0; g < 8; ++g) {
        const int c0 = g * 8;

        for (int i = tid; i < 784; i += 256) {
            int y = i / 28, x = i - y * 28;
            int gy = ty + y - 6, gx = tx + x - 6;
            gy = gy < 0 ? 0 : (gy > 255 ? 255 : gy);
            gx = gx < 0 ? 0 : (gx > 255 ? 255 : gx);
            *reinterpret_cast<short8*>(&raw[i * 8]) =
                *reinterpret_cast<const short8*>(
                    &A[(size_t)((b << 16) + (gy << 8) + gx) * 128 + c0]);
        }
        __syncthreads();

        for (int i = tid; i < 616; i += 256) {   // 28 rows x 22 cols
            int r = i / 22, cc = i - r * 22;
            float s[8];
            #pragma unroll
            for (int c = 0; c < 8; ++c) s[c] = 0.f;
            #pragma unroll
            for (int j = 0; j < 7; ++j) {
                short8 v = *reinterpret_cast<const short8*>(&raw[(r * 28 + cc + j) * 8]);
                float w = gw(j);
                #pragma unroll
                for (int c = 0; c < 8; ++c) s[c] += w * s2f(v[c]);
            }
            #pragma unroll
            for (int c = 0; c < 8; ++c) hb[i * 12 + c] = s[c];
        }
        __syncthreads();

        for (int i = tid; i < 484; i += 256) {   // 22 x 22
            int y = i / 22, x = i - y * 22;
            float s[8];
            #pragma unroll
            for (int c = 0; c < 8; ++c) s[c] = 0.f;
            #pragma unroll
            for (int j = 0; j < 7; ++j) {
                const float* hp = &hb[((y + j) * 22 + x) * 12];
                float w = gw(j);
                #pragma unroll
                for (int c = 0; c < 8; ++c) s[c] += w * hp[c];
            }
            int gy = ty + y - 3, gx = tx + x - 3;
            bool okp = (gy >= 0 && gy < 256 && gx >= 0 && gx < 256);
            #pragma unroll
            for (int c = 0; c < 8; ++c) bl[i * 12 + c] = okp ? s[c] : 0.f;
        }
        __syncthreads();

        short8 f2v = *reinterpret_cast<const short8*>(
            &A[(size_t)((b << 16) + ((ty + py) << 8) + tx + px) * 128 + 64 + c0]);
        float f2f[8];
        #pragma unroll
        for (int c = 0; c < 8; ++c) f2f[c] = s2f(f2v[c]);

        const float* blp = &bl[(py * 22 + px) * 12];
        #pragma unroll
        for (int i = 0; i < 7; ++i)
            #pragma unroll
            for (int j = 0; j < 7; ++j) {
                const float* cell = blp + (i * 22 + j) * 12;
                f32x4 lo = *reinterpret_cast<const f32x4*>(cell);
                f32x4 hi = *reinterpret_cast<const f32x4*>(cell + 4);
                float a = acc[i * 7 + j];
                float d;
                d = f2f[0] - lo.x; a += d * d;
                d = f2f[1] - lo.y; a += d * d;
                d = f2f[2] - lo.z; a += d * d;
                d = f2f[3] - lo.w; a += d * d;
                d = f2f[4] - hi.x; a += d * d;
                d = f2f[5] - hi.y; a += d * d;
                d = f2f[6] - hi.z; a += d * d;
                d = f2f[7] - hi.w; a += d * d;
                acc[i * 7 + j] = a;
            }
        __syncthreads();
    }

    const size_t base = (size_t)((b << 16) + ((ty + py) << 8) + tx + px) * 64;
    float tot = 0.f;
    #pragma unroll
    for (int k = 0; k < 49; ++k) {
        float m = acc[k] * (1.f / 64.f);
        lcPad[base + k] = f2s(m);
        tot += m;
    }
    #pragma unroll
    for (int k = 49; k < 64; ++k) lcPad[base + k] = 0;

    for (int o = 32; o; o >>= 1) tot += __shfl_down(tot, o);
    if ((tid & 63) == 0) red[tid >> 6] = tot;
    __syncthreads();
    if (tid == 0) atomicAdd(lcsum + b, red[0] + red[1] + red[2] + red[3]);
}

__global__ __launch_bounds__(256) void lc_norm_k(short* __restrict__ lc,
                                                 const float* __restrict__ ls, int n4)
{
    int i = blockIdx.x * 256 + threadIdx.x;
    if (i >= n4) return;
    int b = (i * 4) >> 22;
    float sc = 1.f / (ls[b] * (1.f / 3211264.f) + 1e-6f);
    ushort4 u = reinterpret_cast<ushort4*>(lc)[i];
    u.x = (unsigned short)f2s(s2f((short)u.x) * sc);
    u.y = (unsigned short)f2s(s2f((short)u.y) * sc);
    u.z = (unsigned short)f2s(s2f((short)u.z) * sc);
    u.w = (unsigned short)f2s(s2f((short)u.w) * sc);
    reinterpret_cast<ushort4*>(lc)[i] = u;
}

// ---------------------------------------------------------------------------
// Head conv: NHWC bf16 [b,px,16] -> NCHW fp32 planes [b*2+oc][px].
// ---------------------------------------------------------------------------
__global__ __launch_bounds__(256) void head_k(const short* __restrict__ e3,
                                              const float* __restrict__ w,
                                              const float* __restrict__ bias,
                                              float* __restrict__ hd)
{
    int pix = blockIdx.x * 256 + threadIdx.x;
    int b = pix >> 16, rem = pix & 65535;
    int y = rem >> 8, x = rem & 255;
    float a0 = bias[0], a1 = bias[1];
    #pragma unroll
    for (int tap = 0; tap < 9; ++tap) {
        int yy = y + tap / 3 - 1, xx = x + tap % 3 - 1;
        if ((unsigned)yy >= 256u || (unsigned)xx >= 256u) continue;
        const short* p = e3 + (size_t)((b << 16) + (yy << 8) + xx) * 16;
        #pragma unroll
        for (int ic = 0; ic < 16; ++ic) {
            float v = s2f(p[ic]);
            a0 += v * w[ic * 9 + tap];
            a1 += v * w[(16 + ic) * 9 + tap];
        }
    }
    hd[(size_t)(b * 2) * 65536 + rem]     = a0;
    hd[(size_t)(b * 2 + 1) * 65536 + rem] = a1;
}

// ---------------------------------------------------------------------------
// Final separable 7-tap gaussian blur (replicate edges), fp32 planes.
// ---------------------------------------------------------------------------
__global__ __launch_bounds__(256) void blur7f_k(const float* __restrict__ in,
                                                float* __restrict__ out)
{
    __shared__ float raw[22 * 22];
    __shared__ float hb[22 * 16];
    const int tid = threadIdx.x;
    const int tx = (blockIdx.x & 15) << 4;
    const int ty = (blockIdx.x >> 4) << 4;
    const size_t ch = ((size_t)blockIdx.y) << 16;
    const int py = tid >> 4, px = tid & 15;

    for (int i = tid; i < 484; i += 256) {
        int y = i / 22, x = i - y * 22;
        int gy = ty + y - 3, gx = tx + x - 3;
        gy = gy < 0 ? 0 : (gy > 255 ? 255 : gy);
        gx = gx < 0 ? 0 : (gx > 255 ? 255 : gx);
        raw[i] = in[ch + (gy << 8) + gx];
    }
    __syncthreads();
    for (int i = tid; i < 352; i += 256) {
        int r = i >> 4, cc = i & 15;
        float s = 0.f;
        #pragma unroll
        for (int j = 0; j < 7; ++j) s += gw(j) * raw[r * 22 + cc + j];
        hb[i] = s;
    }
    __syncthreads();
    float s = 0.f;
    #pragma unroll
    for (int j = 0; j < 7; ++j) s += gw(j) * hb[(py + j) * 16 + px];
    out[ch + ((ty + py) << 8) + tx + px] = s;
}

// ---------------------------------------------------------------------------
extern "C" void kernel_launch(void* const* d_in, const int* in_sizes, int n_in,
                              void* d_out, int out_size, void* d_ws, size_t ws_size,
                              hipStream_t stream)
{
    const float* feat1  = (const float*)d_in[0];
    const float* feat2  = (const float*)d_in[1];
    const float* pre_w  = (const float*)d_in[2];
    const float* pre_b  = (const float*)d_in[3];
    const float* fc1_w  = (const float*)d_in[4];
    const float* fc1_g  = (const float*)d_in[5];
    const float* fc1_be = (const float*)d_in[6];
    const float* fc2_w  = (const float*)d_in[7];
    const float* fc2_b  = (const float*)d_in[8];
    const float* e1_w   = (const float*)d_in[9];
    const float* e1_g   = (const float*)d_in[10];
    const float* e1_be  = (const float*)d_in[11];
    const float* e2_w   = (const float*)d_in[12];
    const float* e2_g   = (const float*)d_in[13];
    const float* e2_be  = (const float*)d_in[14];
    const float* e3_w   = (const float*)d_in[15];
    const float* e3_g   = (const float*)d_in[16];
    const float* e3_be  = (const float*)d_in[17];
    const float* head_w = (const float*)d_in[18];
    const float* head_b = (const float*)d_in[19];
    float* out = (float*)d_out;

    const size_t NEED = 152000000;
    if (ws_size < NEED) return;

    char* ws = (char*)d_ws;
    short* T1      = (short*)(ws);
    short* T2      = (short*)(ws + 33554432);
    short* lcPad   = (short*)(ws);
    short* featBuf = (short*)(ws + 33554432);
    short* A       = (short*)(ws + 67108864);
    short* FC1o    = (short*)(ws + 83886080);
    short* E1o     = (short*)(ws + 67108864);
    short* E2o     = (short*)(ws + 100663296);
    short* E3o     = (short*)(ws + 117440512);
    float* HD      = (float*)(ws + 125829120);
    short* preW    = (short*)(ws + 150994944);
    short* fc1W    = (short*)(ws + 151068672);
    short* fc2W    = (short*)(ws + 151363584);
    short* e1W     = (short*)(ws + 151511040);
    short* e2W     = (short*)(ws + 151658496);
    short* e3W     = (short*)(ws + 151695360);
    float* sums0   = (float*)(ws + 151704576);
    float* sums1   = (float*)(ws + 151708672);
    float* sums2   = (float*)(ws + 151712768);
    float* sums3   = (float*)(ws + 151716864);
    float* stats0  = (float*)(ws + 151720960);
    float* stats1  = (float*)(ws + 151725056);
    float* stats2  = (float*)(ws + 151729152);
    float* stats3  = (float*)(ws + 151733248);
    float* LS      = (float*)(ws + 151737344);

    hipMemsetAsync(ws + 151704576, 0, 32784, stream);

    transpose_k<<<dim3(1024, 4), 256, 0, stream>>>(feat1, T1);
    transpose_k<<<dim3(1024, 4), 256, 0, stream>>>(feat2, T2);

    repack2_k<<<144, 256, 0, stream>>>(pre_w, preW, 64, 64, 64);
    repack2_k<<<576, 256, 0, stream>>>(fc1_w, fc1W, 128, 128, 128);
    repack2_k<<<288, 256, 0, stream>>>(fc2_w, fc2W, 64, 128, 128);
    repack2_k<<<288, 256, 0, stream>>>(e1_w, e1W, 64, 113, 128);
    repack2_k<<<72, 256, 0, stream>>>(e2_w, e2W, 32, 64, 64);
    repack2_k<<<18, 256, 0, stream>>>(e3_w, e3W, 16, 32, 32);

    // pre conv (cout=64): G=4, NOC=4, WY=1 -> block 256px x 64oc
    convmfma_k<1, 64, 1, 4, 4><<<dim3(256, 1, 4), 256, 0, stream>>>(
        T1, T1, 64, 64, 64, preW, pre_b, A, 128, 0, 0);
    convmfma_k<1, 64, 1, 4, 4><<<dim3(256, 1, 4), 256, 0, stream>>>(
        T2, T2, 64, 64, 64, preW, pre_b, A, 128, 64, 0);

    // local correlation + normalize
    corr_k<<<dim3(256, 4), 256, 0, stream>>>(A, lcPad, LS);
    lc_norm_k<<<16384, 256, 0, stream>>>(lcPad, LS, 4194304);

    // fc1 (cout=128): G=4, NOC=4, WY=2 -> block 128px x 128oc; batch-phased
    for (int b = 3; b >= 0; --b)
        convmfma_k<1, 128, 2, 4, 4><<<dim3(512, 1, 1), 256, 0, stream>>>(
            A, A, 128, 128, 128, fc1W, nullptr, FC1o, 128, 0, b);
    in_stats_nhwc_k<<<dim3(128, 4), 256, 0, stream>>>(FC1o, sums0, 128, 7);
    in_finalize_k<<<2, 256, 0, stream>>>(sums0, stats0, 512);
    in_apply_nhwc_k<<<32768, 256, 0, stream>>>(FC1o, stats0, fc1_g, fc1_be, 128, 7, 8388608);

    // fc2 (cout=64): G=4, NOC=4, WY=1
    convmfma_k<1, 128, 1, 4, 4><<<dim3(256, 1, 4), 256, 0, stream>>>(
        FC1o, FC1o, 128, 128, 128, fc2W, fc2_b, featBuf, 64, 0, 0);

    // e1 (cout=64): concat(featBuf, lcPad)
    convmfma_k<1, 128, 1, 4, 4><<<dim3(256, 1, 4), 256, 0, stream>>>(
        featBuf, lcPad, 64, 64, 64, e1W, nullptr, E1o, 64, 0, 0);
    in_stats_nhwc_k<<<dim3(128, 4), 256, 0, stream>>>(E1o, sums1, 64, 6);
    in_finalize_k<<<1, 256, 0, stream>>>(sums1, stats1, 256);
    in_apply_nhwc_k<<<16384, 256, 0, stream>>>(E1o, stats1, e1_g, e1_be, 64, 6, 4194304);

    // e2 (cout=32): dil=2, G=4, NOC=2
    convmfma_k<2, 64, 1, 2, 4><<<dim3(256, 1, 4), 256, 0, stream>>>(
        E1o, E1o, 64, 64, 64, e2W, nullptr, E2o, 32, 0, 0);
    in_stats_nhwc_k<<<dim3(128, 4), 256, 0, stream>>>(E2o, sums2, 32, 5);
    in_finalize_k<<<1, 256, 0, stream>>>(sums2, stats2, 128);
    in_apply_nhwc_k<<<8192, 256, 0, stream>>>(E2o, stats2, e2_g, e2_be, 32, 5, 2097152);

    // e3 (cout=16): dil=4, G=4, NOC=1
    convmfma_k<4, 32, 1, 1, 4><<<dim3(256, 1, 4), 256, 0, stream>>>(
        E2o, E2o, 32, 32, 32, e3W, nullptr, E3o, 16, 0, 0);
    in_stats_nhwc_k<<<dim3(128, 4), 256, 0, stream>>>(E3o, sums3, 16, 4);
    in_finalize_k<<<1, 256, 0, stream>>>(sums3, stats3, 64);
    in_apply_nhwc_k<<<4096, 256, 0, stream>>>(E3o, stats3, e3_g, e3_be, 16, 4, 1048576);

    head_k<<<1024, 256, 0, stream>>>(E3o, head_w, head_b, HD);
    blur7f_k<<<dim3(256, 8), 256, 0, stream>>>(HD, out);
}